// Round 24
// baseline (98.045 us; speedup 1.0000x reference)
//
#include <hip/hip_runtime.h>
#include <math.h>

#define NC 8192
#define NF 16384
#define NT 24576
#define RN 12288
#define QN 6144
#define LASTD 1e-4f
#define PI_F 3.14159265358979323846f

// ws layout (float offsets)
#define WS_CONST 0
#define WS_TFINE 64
#define WS_SIGCO (WS_TFINE + NF)
#define WS_COLCO (WS_SIGCO + NC)
#define WS_SIGFI (WS_COLCO + 3*NC)
#define WS_COLFI (WS_SIGFI + NF)
#define WS_SRT   (WS_COLFI + 3*NF)
#define WS_RAD   (WS_SRT + 5*NT)
#define WS_CDF   (WS_RAD + 4*NT)
#define WS_WT    (WS_CDF + NC)          // fp8 weights, 66 chunks * 8192 B = 135168 floats
#define WS_FP    (WS_WT + 135168)       // 24 block sums
#define WS_CP    (WS_FP + 32)           // 24*3 color partials
#define WS_CP2   (WS_CP + 128)          // 8*3 coarse color partials
#define WS_RAD4  (WS_CP2 + 32)          // 4*NT sorted quarters

typedef __attribute__((ext_vector_type(4))) float f32x4;
typedef __attribute__((ext_vector_type(2))) long i64x2;

static __device__ inline unsigned char f2e4m3(float x){
  unsigned pk = (unsigned)__builtin_amdgcn_cvt_pk_fp8_f32(x, 0.f, 0, false);
  return (unsigned char)(pk & 0xff);
}
static __device__ inline float e4m3f(unsigned char b){
  return __builtin_amdgcn_cvt_f32_fp8((int)b, 0);
}

// ---------------- prep: weights -> fp8 chunks; block 528 does scalar prep ----------------
__global__ __launch_bounds__(256) void k_prep_w(
    const float* __restrict__ W0, const float* __restrict__ Wh,
    unsigned char* __restrict__ Wt,
    const float* hor_, const float* ver_, const float* tm,
    const float* near_, const float* far_,
    const float* Wcol, const float* bcol, float* cst)
{
  if (blockIdx.x == 528) {
    if (threadIdx.x != 0) return;
    float hor = hor_[0], ver = ver_[0], nearv = near_[0], farv = far_[0];
    float dw[3];
    for (int j = 0; j < 3; ++j)
      dw[j] = tm[j*4+0]*hor + tm[j*4+1]*ver + tm[j*4+2] + tm[j*4+3];
    float enc[24];
    for (int i = 0; i < 3; ++i)
      for (int l = 0; l < 4; ++l) {
        float f = PI_F * exp2f(2.f*(float)l);
        float ang = dw[i]*f;
        enc[i*8 + l*2]     = sinf(ang);
        enc[i*8 + l*2 + 1] = cosf(ang);
      }
    for (int c = 0; c < 3; ++c) {
      float s = bcol[c];
      for (int d = 0; d < 24; ++d) s += enc[d]*Wcol[d*3+c];
      cst[6+c] = s;
    }
    for (int j = 0; j < 3; ++j) {
      cst[0+j] = tm[j*4+0]*hor + tm[j*4+1]*ver + tm[j*4+3];
      cst[3+j] = tm[j*4+2];
    }
    cst[9]  = nearv;
    cst[10] = (farv - nearv) / (float)(NC - 1);
    cst[11] = (farv - nearv) / (float)NC;
    return;
  }
  int base = (blockIdx.x*256 + threadIdx.x)*4;
  for (int e = base; e < base+4; ++e) {
    int c = e >> 13;
    if (c >= 66) break;
    int r = e & 8191;
    int w_ = r >> 10;
    int q = r & 1023;
    int ln = q >> 4;
    int rest = q & 15;
    int mt = rest >> 3, j = rest & 7;
    int out = (w_*2 + mt)*16 + (ln & 15);
    int kk = (ln >> 4)*8 + j;
    float v;
    if (c < 2) {
      int k = c*32 + kk;
      v = (k < 60) ? W0[k*256 + out] : 0.f;
    } else {
      int m = (c-2) >> 3, kc = (c-2) & 7;
      v = Wh[m*65536 + (kc*32+kk)*256 + out];
    }
    Wt[e] = f2e4m3(v);
  }
}

// ---------------- MFMA MLP: fp8, 8 waves x 2 M-tiles, depth-8 ring, QUAD gates (17 total) ----------------
template<int NTL>   // points per block = NTL*16 (NTL=2)
__global__ __launch_bounds__(512, 1) void k_mlp_mfma(
    const float* __restrict__ cst, const unsigned char* __restrict__ Wt,
    const float* __restrict__ b0, const float* __restrict__ bh,
    const float* __restrict__ Wsig, const float* __restrict__ bsig,
    const float* __restrict__ Wcol,
    const float* __restrict__ tf, int npts,
    float* __restrict__ sig_out, float* __restrict__ col_out)
{
  __shared__ __align__(16) unsigned char hbuf[NTL*16*256];    // NTL*4 KB (fp8)
  __shared__ __align__(16) float bbuf[9*256];                 // 9 KB biases
  const int tid = threadIdx.x;
  const int w = tid >> 6, lane = tid & 63;
  const int lo = lane & 15, hi = lane >> 4;
  const int p0 = blockIdx.x * (NTL*16);

  // ---- positional encoding: 1 sincos + double-angle ladder per (point,dim); fp8 store ----
  if (tid < NTL*16*3) {
    int p = tid / 3, i = tid - p*3;
    int gp = p0 + p;
    float step = cst[10], nearv = cst[9];
    float t = tf ? tf[gp] : fmaf(step, (float)gp, nearv);
    float x = fmaf(cst[3+i], t, cst[0+i]);
    float s, c;
    sincosf(PI_F * x, &s, &c);
    unsigned char* row = &hbuf[p*256];
    #pragma unroll
    for (int l = 0; l < 10; ++l) {
      int d0 = i*20 + l*2;
      row[((((d0  )>>3) ^ (p&7))<<3) + ((d0  )&7)] = f2e4m3(s);
      row[((((d0+1)>>3) ^ (p&7))<<3) + ((d0+1)&7)] = f2e4m3(c);
      float s2 = 2.f*s*c, c2 = (c-s)*(c+s);
      s = 2.f*s2*c2; c = (c2-s2)*(c2+s2);
    }
    if (i == 0) {
      #pragma unroll
      for (int d = 60; d < 64; ++d)
        row[(((d>>3) ^ (p&7))<<3) + (d&7)] = 0;
    }
  }
  // ---- biases -> LDS (epilogue never touches vmcnt) ----
  for (int i = tid; i < 9*256; i += 512) {
    int j = i >> 8, t = i & 255;
    bbuf[i] = (j == 0) ? b0[t] : bh[(j-1)*256 + t];
  }
  __syncthreads();   // clean counters before prefetch choreography

  // B-frag base byte offsets (addr(KK,ni) = boff[ni] ^ (KK<<5))
  unsigned boff[NTL];
  #pragma unroll
  for (int ni = 0; ni < NTL; ++ni) {
    int pp = ni*16 + lo;
    boff[ni] = (unsigned)(pp*256 + ((hi ^ (pp&7))<<3));
  }
  const unsigned voff = (unsigned)(w*1024 + lane*16);   // invariant A-load voffset
  i64x2 S0,S1,S2,S3,S4,S5,S6,S7;
  f32x4 acc[2][NTL];

#define GLD1(ra,cc) do{ \
  const unsigned char* s_ = Wt + ((size_t)(cc))*8192; \
  asm volatile("global_load_dwordx4 %0, %1, %2" \
    : "=&v"(ra) : "v"(voff), "s"(s_)); }while(0)

#define MM2(ra,bfr_) do{ \
  _Pragma("unroll") \
  for(int ni=0;ni<NTL;++ni){ \
    acc[0][ni]=__builtin_amdgcn_mfma_f32_16x16x32_fp8_fp8(ra[0],bfr_[ni],acc[0][ni],0,0,0); \
    acc[1][ni]=__builtin_amdgcn_mfma_f32_16x16x32_fp8_fp8(ra[1],bfr_[ni],acc[1][ni],0,0,0); } \
}while(0)

#define BRD(bfr_,KK) do{ \
  _Pragma("unroll") \
  for(int ni=0;ni<NTL;++ni) \
    bfr_[ni] = *(const long*)((const char*)hbuf + (boff[ni] ^ ((unsigned)(KK)<<5))); \
}while(0)

// quad gate: B reads for 4 chunks -> one vmcnt(WN) -> 16*NTL/2 MFMAs -> optional reissue of the 4 slots
#define STEP4R(ra,rb,rc,rd,K0,NCA) do{ \
  long bA_[NTL], bB_[NTL], bC_[NTL], bD_[NTL]; \
  BRD(bA_,(K0)); BRD(bB_,(K0)+1); BRD(bC_,(K0)+2); BRD(bD_,(K0)+3); \
  asm volatile("s_waitcnt vmcnt(4)":::"memory"); \
  __builtin_amdgcn_sched_barrier(0); \
  MM2(ra,bA_); MM2(rb,bB_); MM2(rc,bC_); MM2(rd,bD_); \
  __builtin_amdgcn_sched_barrier(0); \
  GLD1(ra,(NCA)); GLD1(rb,(NCA)+1); GLD1(rc,(NCA)+2); GLD1(rd,(NCA)+3); \
}while(0)

#define STEP4F(ra,rb,rc,rd,K0,WN) do{ \
  long bA_[NTL], bB_[NTL], bC_[NTL], bD_[NTL]; \
  BRD(bA_,(K0)); BRD(bB_,(K0)+1); BRD(bC_,(K0)+2); BRD(bD_,(K0)+3); \
  asm volatile("s_waitcnt vmcnt(" #WN ")":::"memory"); \
  __builtin_amdgcn_sched_barrier(0); \
  MM2(ra,bA_); MM2(rb,bB_); MM2(rc,bC_); MM2(rd,bD_); \
  __builtin_amdgcn_sched_barrier(0); \
}while(0)

  auto zacc = [&]() {
    const f32x4 z4 = {0.f,0.f,0.f,0.f};
    #pragma unroll
    for (int mi=0;mi<2;++mi)
      #pragma unroll
      for (int ni=0;ni<NTL;++ni) acc[mi][ni] = z4;
  };
  auto epilogue = [&](int l, bool relu) {
    const float* bias = &bbuf[l*256];
    #pragma unroll
    for (int mi=0;mi<2;++mi) {
      int mt = w*2+mi;
      f32x4 bv = *(const f32x4*)&bias[mt*16 + hi*4];   // LDS read (lgkm)
      #pragma unroll
      for (int ni=0;ni<NTL;++ni) {
        f32x4 v = acc[mi][ni];
        float o0=v[0]+bv[0], o1=v[1]+bv[1], o2=v[2]+bv[2], o3=v[3]+bv[3];
        if (relu){o0=fmaxf(o0,0.f);o1=fmaxf(o1,0.f);o2=fmaxf(o2,0.f);o3=fmaxf(o3,0.f);}
        unsigned pk = (unsigned)__builtin_amdgcn_cvt_pk_fp8_f32(o0, o1, 0, false);
        pk = (unsigned)__builtin_amdgcn_cvt_pk_fp8_f32(o2, o3, (int)pk, true);
        int pp = ni*16 + lo;
        int colu = mt*16 + hi*4;
        int sl = colu >> 3, off = colu & 7;
        *(unsigned*)((char*)hbuf + pp*256 + ((sl^(pp&7))<<3) + off) = pk;
      }
    }
  };

  // prologue: 8 chunks (8 loads) in flight: S0..S7 <- chunks 0..7
  GLD1(S0,0); GLD1(S1,1); GLD1(S2,2); GLD1(S3,3);
  GLD1(S4,4); GLD1(S5,5); GLD1(S6,6); GLD1(S7,7);

  // ---- layer 0: chunks 0,1 (S0,S1) in one gate at vmcnt(6); reissue S0<-8, S1<-9 ----
  zacc();
  {
    long bA_[NTL], bB_[NTL];
    BRD(bA_,0); BRD(bB_,1);
    asm volatile("s_waitcnt vmcnt(6)":::"memory");
    __builtin_amdgcn_sched_barrier(0);
    MM2(S0,bA_); MM2(S1,bB_);
    __builtin_amdgcn_sched_barrier(0);
    GLD1(S0,8); GLD1(S1,9);
  }
  __builtin_amdgcn_s_barrier();
  epilogue(0, true);
  asm volatile("s_waitcnt lgkmcnt(0)":::"memory");
  __builtin_amdgcn_sched_barrier(0);
  __builtin_amdgcn_s_barrier();

  // ---- layers 1..7: 2 quad gates each; S2..S5 = KK0..3, S6,S7,S0,S1 = KK4..7 ----
  #pragma unroll 1
  for (int l = 1; l < 8; ++l) {
    zacc();
    const int nx = 2 + l*8;   // next layer's chunk base
    STEP4R(S2,S3,S4,S5, 0, nx+0);
    STEP4R(S6,S7,S0,S1, 4, nx+4);
    __builtin_amdgcn_s_barrier();   // all waves done reading hbuf
    epilogue(l, true);
    asm volatile("s_waitcnt lgkmcnt(0)":::"memory");
    __builtin_amdgcn_sched_barrier(0);
    __builtin_amdgcn_s_barrier();   // new h visible
  }

  // ---- layer 8: drain tail (vmcnt 4 then 0) ----
  zacc();
  STEP4F(S2,S3,S4,S5, 0, 4);
  STEP4F(S6,S7,S0,S1, 4, 0);
  __builtin_amdgcn_s_barrier();
  epilogue(8, false);
  asm volatile("s_waitcnt lgkmcnt(0)":::"memory");
  __builtin_amdgcn_sched_barrier(0);
  __builtin_amdgcn_s_barrier();
#undef GLD1
#undef MM2
#undef BRD
#undef STEP4R
#undef STEP4F

  // ---- heads: 4 threads per point, 64 k each; fp32 head weights, fp8 h ----
  if (tid < NTL*64) {
    int p = tid >> 2, s = tid & 3;
    float as_=0.f, a0=0.f, a1=0.f, a2=0.f;
    for (int q=0;q<8;++q) {
      int slot = s*8+q;
      const unsigned char* hb = &hbuf[p*256 + ((slot^(p&7))<<3)];
      #pragma unroll
      for (int j=0;j<8;++j) {
        float hf = e4m3f(hb[j]);
        int k = s*64 + q*8 + j;
        as_ = fmaf(hf, Wsig[k], as_);
        const float* wc = Wcol + 72 + k*3;
        a0 = fmaf(hf, wc[0], a0);
        a1 = fmaf(hf, wc[1], a1);
        a2 = fmaf(hf, wc[2], a2);
      }
    }
    as_ += __shfl_xor(as_,1); as_ += __shfl_xor(as_,2);
    a0 += __shfl_xor(a0,1); a0 += __shfl_xor(a0,2);
    a1 += __shfl_xor(a1,1); a1 += __shfl_xor(a1,2);
    a2 += __shfl_xor(a2,1); a2 += __shfl_xor(a2,2);
    if (s == 0) {
      sig_out[p0+p] = 1.f/(1.f+expf(-(as_ + bsig[0])));
      col_out[0*npts + p0+p] = 1.f/(1.f+expf(-(a0 + cst[6])));
      col_out[1*npts + p0+p] = 1.f/(1.f+expf(-(a1 + cst[7])));
      col_out[2*npts + p0+p] = 1.f/(1.f+expf(-(a2 + cst[8])));
    }
  }
}

// ---------------- mid: redundant block-local scan + ccoarse partials (blocks<8) + invcdf (16 blocks) ----------------
__global__ __launch_bounds__(1024) void k_mid(
    const float* __restrict__ sigco, const float* __restrict__ colco,
    const float* __restrict__ cst, float* __restrict__ tfine,
    float* __restrict__ cpart2)
{
  __shared__ float cdf[NC];   // 32 KB
  __shared__ float wsum[16];
  __shared__ float r0[16], r1[16], r2[16];
  const int tid = threadIdx.x;
  const int lane = tid & 63, wid = tid >> 6;

  // block-local scan of sigco (identical arithmetic in every block -> deterministic)
  float v[8], inc[8];
  float run = 0.f;
  #pragma unroll
  for (int j = 0; j < 8; ++j) { v[j] = sigco[tid*8+j]; run += v[j]; inc[j] = run; }
  float sc = run;
  #pragma unroll
  for (int off = 1; off < 64; off <<= 1) {
    float t = __shfl_up(sc, off);
    if (lane >= off) sc += t;
  }
  if (lane == 63) wsum[wid] = sc;
  __syncthreads();
  if (tid < 16) {
    float wv = wsum[tid];
    float s2 = wv;
    #pragma unroll
    for (int off = 1; off < 16; off <<= 1) {
      float t = __shfl_up(s2, off);
      if (tid >= off) s2 += t;
    }
    wsum[tid] = s2 - wv;
  }
  __syncthreads();
  float excl = wsum[wid] + (sc - run);
  #pragma unroll
  for (int j = 0; j < 8; ++j) cdf[tid*8+j] = excl + inc[j];
  __syncthreads();

  // blocks 0..7: C_coarse partials for their 1024-element slice
  if (blockIdx.x < 8) {
    int i = blockIdx.x*1024 + tid;
    float dco = cst[11];
    float T = expf(-dco*cdf[i]);
    float w = T*(1.f-expf(-dco*sigco[i]));
    float a0 = colco[i]*w, a1 = colco[NC+i]*w, a2 = colco[2*NC+i]*w;
    #pragma unroll
    for (int off = 32; off; off >>= 1) {
      a0 += __shfl_down(a0, off); a1 += __shfl_down(a1, off); a2 += __shfl_down(a2, off);
    }
    if (lane==0) { r0[wid]=a0; r1[wid]=a1; r2[wid]=a2; }
    __syncthreads();
    if (tid==0) {
      float s0=0,s1=0,s2=0;
      for (int k=0;k<16;++k){s0+=r0[k];s1+=r1[k];s2+=r2[k];}
      cpart2[blockIdx.x*3+0]=s0; cpart2[blockIdx.x*3+1]=s1; cpart2[blockIdx.x*3+2]=s2;
    }
  }

  // all 16 blocks: inverse-CDF for their 1024 samples (LDS-resident cdf)
  int j = blockIdx.x*1024 + tid;
  float cdf0 = cdf[0], cdfN = cdf[NC-1];
  float stepi = (cdfN - cdf0) / (float)(NF+1);
  float nearv = cst[9], dt = cst[10];
  float tv = cdf0 + (float)(j+1)*stepi;
  int lo = 0, hi = NC;
  while (lo < hi) { int mid = (lo+hi)>>1; if (cdf[mid] < tv) lo = mid+1; else hi = mid; }
  int idx = lo-1; idx = idx < 0 ? 0 : (idx > NC-2 ? NC-2 : idx);
  float sig1 = sigco[idx+1];
  tfine[j] = fmaf(dt, (float)idx, nearv) + (tv - cdf[idx]) * (dt / sig1);
}

// ---------------- radix sort: 16 blocks (4 arrays x 4 quarters of 6144), keys in regs ----------------
__global__ __launch_bounds__(1024) void k_radix4(
    const float* __restrict__ sigco, const float* __restrict__ colco,
    const float* __restrict__ sigfi, const float* __restrict__ colfi,
    float* __restrict__ rad4)
{
  __shared__ unsigned int buf[QN];       // 24KB
  __shared__ unsigned int wh[16][256];   // 16KB
  __shared__ unsigned int tot[256];
  __shared__ unsigned int dbase[256];
  const int tid = threadIdx.x;
  const int w = tid >> 6, lane = tid & 63;
  const int a = blockIdx.x >> 2, qq = blockIdx.x & 3;
  const unsigned long long below = (1ull << lane) - 1ull;

  unsigned int key[6];
  #pragma unroll
  for (int j = 0; j < 6; ++j) {
    int i = w*384 + j*64 + lane;   // enumeration order = storage order
    int g = qq*QN + i;
    float v;
    if (a < 3) v = (g < NC) ? colco[a*NC+g] : colfi[a*NF + (g-NC)];
    else       v = (g < NC) ? sigco[g] : sigfi[g-NC];
    key[j] = __float_as_uint(v);
  }

  for (int p = 0; p < 4; ++p) {
    const int sh = p*8;
    for (int i = tid; i < 16*256; i += 1024) ((unsigned int*)wh)[i] = 0;
    __syncthreads();
    unsigned int lrk[6];
    #pragma unroll
    for (int j = 0; j < 6; ++j) {
      unsigned int d = (key[j] >> sh) & 255u;
      unsigned long long m = ~0ull;
      #pragma unroll
      for (int b = 0; b < 8; ++b) {
        unsigned long long bb = __ballot((d >> b) & 1u);
        m &= ((d >> b) & 1u) ? bb : ~bb;
      }
      unsigned int rkl = (unsigned int)__popcll(m & below);
      unsigned int base = wh[w][d];
      if (rkl == 0) wh[w][d] = base + (unsigned int)__popcll(m);
      lrk[j] = base + rkl;
    }
    __syncthreads();
    if (tid < 256) {
      unsigned int run2 = 0;
      #pragma unroll
      for (int ww = 0; ww < 16; ++ww) { unsigned int c = wh[ww][tid]; wh[ww][tid] = run2; run2 += c; }
      tot[tid] = run2;
    }
    __syncthreads();
    if (tid < 64) {
      unsigned int t0=tot[tid*4], t1=tot[tid*4+1], t2=tot[tid*4+2], t3=tot[tid*4+3];
      unsigned int ssum = t0+t1+t2+t3;
      unsigned int sc = ssum;
      for (int off=1; off<64; off<<=1) { unsigned int vv = __shfl_up((int)sc, off); if (lane>=off) sc += vv; }
      unsigned int ex = sc - ssum;
      dbase[tid*4] = ex; dbase[tid*4+1] = ex+t0; dbase[tid*4+2] = ex+t0+t1; dbase[tid*4+3] = ex+t0+t1+t2;
    }
    __syncthreads();
    #pragma unroll
    for (int j = 0; j < 6; ++j) {
      unsigned int d = (key[j] >> sh) & 255u;
      buf[dbase[d] + wh[w][d] + lrk[j]] = key[j];
    }
    __syncthreads();
    if (p < 3) {
      #pragma unroll
      for (int j = 0; j < 6; ++j) key[j] = buf[w*384 + j*64 + lane];
      __syncthreads();
    }
  }
  for (int i = tid; i < QN; i += 1024)
    rad4[a*NT + qq*QN + i] = __uint_as_float(buf[i]);
}

// ---------------- merge quarters -> halves: 16 blocks (4 arrays x 2 halves x 2 segs) ----------------
__global__ __launch_bounds__(1024) void k_merge2(
    const float* __restrict__ rad4, float* __restrict__ rad)
{
  const int a = blockIdx.x >> 2, h = (blockIdx.x >> 1) & 1, s = blockIdx.x & 1;
  const float* A = rad4 + a*NT + (2*h)*QN;
  const float* B = A + QN;
  float* o = rad + a*NT + h*RN;
  int k0 = s*QN + (int)threadIdx.x*6;
  int lo = k0-QN; if (lo < 0) lo = 0;
  int hi = k0 < QN ? k0 : QN;
  while (lo < hi) {
    int mid = (lo+hi)>>1;
    if (A[mid] <= B[k0-mid-1]) lo = mid+1; else hi = mid;
  }
  int i = lo, j = k0 - lo;
  #pragma unroll
  for (int c = 0; c < 6; ++c) {
    float av = (i < QN) ? A[i] : 0.f;
    bool ta = (j >= QN) || (i < QN && av <= B[j]);
    float v = ta ? av : B[j];
    if (ta) ++i; else ++j;
    o[k0+c] = v;
  }
}

// ---------------- merge: 5 rows; row0 = t_coarse(analytic) ∪ t_fine; rows1-4 = sorted halves ----------------
__global__ __launch_bounds__(1024) void k_merge(
    const float* __restrict__ rad, const float* __restrict__ tfine,
    const float* __restrict__ cst, float* __restrict__ srt)
{
  const int row = blockIdx.x >> 2, q = blockIdx.x & 3;
  const float dt = cst[10], nv = cst[9];
  const bool isT = (row == 0);
  const float* A = isT ? (const float*)nullptr : rad + (row-1)*NT;
  const float* B = isT ? tfine : (A + RN);
  const int nA = isT ? NC : RN, nB = isT ? NF : RN;
  int k0 = q*6144 + (int)threadIdx.x*6;
  int lo = k0-nB; if (lo < 0) lo = 0;
  int hi = k0 < nA ? k0 : nA;
  while (lo < hi) {
    int mid = (lo+hi)>>1;
    float av = isT ? fmaf(dt,(float)mid,nv) : A[mid];
    if (av <= B[k0-mid-1]) lo = mid+1; else hi = mid;
  }
  int i = lo, j = k0 - lo;
  float* o = srt + row*NT;
  #pragma unroll
  for (int c = 0; c < 6; ++c) {
    float av = (i < nA) ? (isT ? fmaf(dt,(float)i,nv) : A[i]) : 0.f;
    bool ta = (j >= nB) || (i < nA && av <= B[j]);
    float v = ta ? av : B[j];
    if (ta) ++i; else ++j;
    o[k0+c] = v;
  }
}

// ---------------- final phase 1: per-block sd sums (24 blocks x 1024) ----------------
__global__ __launch_bounds__(1024) void k_fpart(
    const float* __restrict__ srt, float* __restrict__ fpart)
{
  const float* trow = srt;
  const float* sgr = srt + 4*NT;
  __shared__ float wsum[16];
  int i = blockIdx.x*1024 + threadIdx.x;
  const int lane = threadIdx.x & 63, wid = threadIdx.x >> 6;
  float tcur = trow[i];
  float tnext = (i < NT-1) ? trow[i+1] : 0.f;
  float delta = (i == NT-1) ? LASTD : (tnext - tcur);
  float sd = delta * sgr[i];
  float s = sd;
  #pragma unroll
  for (int off = 32; off; off >>= 1) s += __shfl_down(s, off);
  if (lane == 0) wsum[wid] = s;
  __syncthreads();
  if (threadIdx.x == 0) {
    float t = 0.f;
    for (int k = 0; k < 16; ++k) t += wsum[k];
    fpart[blockIdx.x] = t;
  }
}

// ---------------- final phase 2: offset + local scan + weighted color partials ----------------
__global__ __launch_bounds__(1024) void k_fcomb(
    const float* __restrict__ srt, const float* __restrict__ fpart,
    float* __restrict__ cpart)
{
  const float* trow = srt;
  const float* c0r = srt + NT;
  const float* c1r = srt + 2*NT;
  const float* c2r = srt + 3*NT;
  const float* sgr = srt + 4*NT;
  __shared__ float wsum[16];
  __shared__ float r0[16], r1[16], r2[16];
  const int tid = threadIdx.x;
  const int lane = tid & 63, wid = tid >> 6;
  int i = blockIdx.x*1024 + tid;
  float off0 = 0.f;
  for (int k = 0; k < 24; ++k) off0 += (k < (int)blockIdx.x) ? fpart[k] : 0.f;

  float tcur = trow[i];
  float tnext = (i < NT-1) ? trow[i+1] : 0.f;
  float delta = (i == NT-1) ? LASTD : (tnext - tcur);
  float sd = delta * sgr[i];
  // block inclusive scan of sd
  float sc = sd;
  #pragma unroll
  for (int off = 1; off < 64; off <<= 1) {
    float t = __shfl_up(sc, off);
    if (lane >= off) sc += t;
  }
  if (lane == 63) wsum[wid] = sc;
  __syncthreads();
  if (tid < 16) {
    float wv = wsum[tid];
    float s2 = wv;
    #pragma unroll
    for (int off = 1; off < 16; off <<= 1) {
      float t = __shfl_up(s2, off);
      if (tid >= off) s2 += t;
    }
    wsum[tid] = s2 - wv;
  }
  __syncthreads();
  float Sinc = off0 + wsum[wid] + sc;   // global inclusive cumsum at i
  float T = expf(-Sinc);
  float w = T*(1.f-expf(-sd));
  float a0 = c0r[i]*w, a1 = c1r[i]*w, a2 = c2r[i]*w;
  #pragma unroll
  for (int off = 32; off; off >>= 1) {
    a0 += __shfl_down(a0, off); a1 += __shfl_down(a1, off); a2 += __shfl_down(a2, off);
  }
  if (lane==0) { r0[wid]=a0; r1[wid]=a1; r2[wid]=a2; }
  __syncthreads();
  if (tid==0) {
    float s0=0,s1=0,s2=0;
    for (int k=0;k<16;++k){s0+=r0[k];s1+=r1[k];s2+=r2[k];}
    cpart[blockIdx.x*3+0]=s0; cpart[blockIdx.x*3+1]=s1; cpart[blockIdx.x*3+2]=s2;
  }
}

// ---------------- final phase 3: sum partials (coarse 8, fine 24) ----------------
__global__ void k_fsum(const float* __restrict__ cpart, const float* __restrict__ cpart2,
                       float* __restrict__ outv)
{
  int c = threadIdx.x;
  if (c < 3) {
    float s2 = 0.f;
    for (int b = 0; b < 8; ++b) s2 += cpart2[b*3 + c];
    outv[c] = s2;
    float s = 0.f;
    for (int b = 0; b < 24; ++b) s += cpart[b*3 + c];
    outv[3 + c] = s;
  }
}

extern "C" void kernel_launch(void* const* d_in, const int* in_sizes, int n_in,
                              void* d_out, int out_size, void* d_ws, size_t ws_size,
                              hipStream_t stream) {
  (void)in_sizes; (void)n_in; (void)out_size; (void)ws_size;
  const float* hor  = (const float*)d_in[0];
  const float* ver  = (const float*)d_in[1];
  const float* tm   = (const float*)d_in[2];
  const float* nearp= (const float*)d_in[3];
  const float* farp = (const float*)d_in[4];
  const float* W0   = (const float*)d_in[5];
  const float* b0   = (const float*)d_in[6];
  const float* Wh   = (const float*)d_in[7];
  const float* bh   = (const float*)d_in[8];
  const float* Wsig = (const float*)d_in[9];
  const float* bsig = (const float*)d_in[10];
  const float* Wcol = (const float*)d_in[11];
  const float* bcol = (const float*)d_in[12];
  float* out = (float*)d_out;
  float* ws  = (float*)d_ws;

  float* cst   = ws + WS_CONST;
  float* tfine = ws + WS_TFINE;
  float* sigco = ws + WS_SIGCO;
  float* colco = ws + WS_COLCO;
  float* sigfi = ws + WS_SIGFI;
  float* colfi = ws + WS_COLFI;
  float* srt   = ws + WS_SRT;
  float* rad   = ws + WS_RAD;
  float* fpart = ws + WS_FP;
  float* cpart = ws + WS_CP;
  float* cpart2= ws + WS_CP2;
  float* rad4  = ws + WS_RAD4;
  unsigned char* Wt = (unsigned char*)(ws + WS_WT);

  k_prep_w<<<dim3(529), dim3(256), 0, stream>>>(W0, Wh, Wt, hor, ver, tm, nearp, farp,
                                                Wcol, bcol, cst);
  k_mlp_mfma<2><<<dim3(NC/32), dim3(512), 0, stream>>>(cst, Wt, b0, bh, Wsig, bsig, Wcol,
                                                       (const float*)nullptr, NC, sigco, colco);
  k_mid<<<dim3(16), dim3(1024), 0, stream>>>(sigco, colco, cst, tfine, cpart2);
  k_mlp_mfma<2><<<dim3(NF/32), dim3(512), 0, stream>>>(cst, Wt, b0, bh, Wsig, bsig, Wcol,
                                                       (const float*)tfine, NF, sigfi, colfi);
  k_radix4<<<dim3(16), dim3(1024), 0, stream>>>(sigco, colco, sigfi, colfi, rad4);
  k_merge2<<<dim3(16), dim3(1024), 0, stream>>>(rad4, rad);
  k_merge<<<dim3(20), dim3(1024), 0, stream>>>(rad, tfine, cst, srt);
  k_fpart<<<dim3(24), dim3(1024), 0, stream>>>(srt, fpart);
  k_fcomb<<<dim3(24), dim3(1024), 0, stream>>>(srt, fpart, cpart);
  k_fsum<<<dim3(1), dim3(64), 0, stream>>>(cpart, cpart2, out);
}

// Round 25
// 97.124 us; speedup vs baseline: 1.0095x; 1.0095x over previous
//
#include <hip/hip_runtime.h>
#include <math.h>

#define NC 8192
#define NF 16384
#define NT 24576
#define RN 12288
#define QN 6144
#define LASTD 1e-4f
#define PI_F 3.14159265358979323846f

// ws layout (float offsets)
#define WS_CONST 0
#define WS_TFINE 64
#define WS_SIGCO (WS_TFINE + NF)
#define WS_COLCO (WS_SIGCO + NC)
#define WS_SIGFI (WS_COLCO + 3*NC)
#define WS_COLFI (WS_SIGFI + NF)
#define WS_SRT   (WS_COLFI + 3*NF)
#define WS_RAD   (WS_SRT + 5*NT)
#define WS_CDF   (WS_RAD + 4*NT)
#define WS_WT    (WS_CDF + NC)          // fp8 weights, 66 chunks * 8192 B = 135168 floats
#define WS_FP    (WS_WT + 135168)       // 24 block sums
#define WS_CP    (WS_FP + 32)           // 24*3 color partials
#define WS_CP2   (WS_CP + 128)          // 8*3 coarse color partials
#define WS_RAD4  (WS_CP2 + 32)          // 4*NT sorted quarters

typedef __attribute__((ext_vector_type(4))) float f32x4;
typedef __attribute__((ext_vector_type(2))) long i64x2;

static __device__ inline unsigned char f2e4m3(float x){
  unsigned pk = (unsigned)__builtin_amdgcn_cvt_pk_fp8_f32(x, 0.f, 0, false);
  return (unsigned char)(pk & 0xff);
}
static __device__ inline float e4m3f(unsigned char b){
  return __builtin_amdgcn_cvt_f32_fp8((int)b, 0);
}

// ---------------- prep: weights -> fp8 chunks; block 528 does scalar prep ----------------
__global__ __launch_bounds__(256) void k_prep_w(
    const float* __restrict__ W0, const float* __restrict__ Wh,
    unsigned char* __restrict__ Wt,
    const float* hor_, const float* ver_, const float* tm,
    const float* near_, const float* far_,
    const float* Wcol, const float* bcol, float* cst)
{
  if (blockIdx.x == 528) {
    if (threadIdx.x != 0) return;
    float hor = hor_[0], ver = ver_[0], nearv = near_[0], farv = far_[0];
    float dw[3];
    for (int j = 0; j < 3; ++j)
      dw[j] = tm[j*4+0]*hor + tm[j*4+1]*ver + tm[j*4+2] + tm[j*4+3];
    float enc[24];
    for (int i = 0; i < 3; ++i)
      for (int l = 0; l < 4; ++l) {
        float f = PI_F * exp2f(2.f*(float)l);
        float ang = dw[i]*f;
        enc[i*8 + l*2]     = sinf(ang);
        enc[i*8 + l*2 + 1] = cosf(ang);
      }
    for (int c = 0; c < 3; ++c) {
      float s = bcol[c];
      for (int d = 0; d < 24; ++d) s += enc[d]*Wcol[d*3+c];
      cst[6+c] = s;
    }
    for (int j = 0; j < 3; ++j) {
      cst[0+j] = tm[j*4+0]*hor + tm[j*4+1]*ver + tm[j*4+3];
      cst[3+j] = tm[j*4+2];
    }
    cst[9]  = nearv;
    cst[10] = (farv - nearv) / (float)(NC - 1);
    cst[11] = (farv - nearv) / (float)NC;
    return;
  }
  int base = (blockIdx.x*256 + threadIdx.x)*4;
  for (int e = base; e < base+4; ++e) {
    int c = e >> 13;
    if (c >= 66) break;
    int r = e & 8191;
    int w_ = r >> 10;
    int q = r & 1023;
    int ln = q >> 4;
    int rest = q & 15;
    int mt = rest >> 3, j = rest & 7;
    int out = (w_*2 + mt)*16 + (ln & 15);
    int kk = (ln >> 4)*8 + j;
    float v;
    if (c < 2) {
      int k = c*32 + kk;
      v = (k < 60) ? W0[k*256 + out] : 0.f;
    } else {
      int m = (c-2) >> 3, kc = (c-2) & 7;
      v = Wh[m*65536 + (kc*32+kk)*256 + out];
    }
    Wt[e] = f2e4m3(v);
  }
}

// ---------------- MFMA MLP: fp8, 8 waves x 2 M-tiles, depth-8 ring, PAIRED gates (33 vs 66) ----------------
template<int NTL>   // points per block = NTL*16 (NTL=2)
__global__ __launch_bounds__(512, 1) void k_mlp_mfma(
    const float* __restrict__ cst, const unsigned char* __restrict__ Wt,
    const float* __restrict__ b0, const float* __restrict__ bh,
    const float* __restrict__ Wsig, const float* __restrict__ bsig,
    const float* __restrict__ Wcol,
    const float* __restrict__ tf, int npts,
    float* __restrict__ sig_out, float* __restrict__ col_out)
{
  __shared__ __align__(16) unsigned char hbuf[NTL*16*256];    // NTL*4 KB (fp8)
  __shared__ __align__(16) float bbuf[9*256];                 // 9 KB biases
  const int tid = threadIdx.x;
  const int w = tid >> 6, lane = tid & 63;
  const int lo = lane & 15, hi = lane >> 4;
  const int p0 = blockIdx.x * (NTL*16);

  // ---- positional encoding: 1 sincos + double-angle ladder per (point,dim); fp8 store ----
  if (tid < NTL*16*3) {
    int p = tid / 3, i = tid - p*3;
    int gp = p0 + p;
    float step = cst[10], nearv = cst[9];
    float t = tf ? tf[gp] : fmaf(step, (float)gp, nearv);
    float x = fmaf(cst[3+i], t, cst[0+i]);
    float s, c;
    sincosf(PI_F * x, &s, &c);
    unsigned char* row = &hbuf[p*256];
    #pragma unroll
    for (int l = 0; l < 10; ++l) {
      int d0 = i*20 + l*2;
      row[((((d0  )>>3) ^ (p&7))<<3) + ((d0  )&7)] = f2e4m3(s);
      row[((((d0+1)>>3) ^ (p&7))<<3) + ((d0+1)&7)] = f2e4m3(c);
      float s2 = 2.f*s*c, c2 = (c-s)*(c+s);
      s = 2.f*s2*c2; c = (c2-s2)*(c2+s2);
    }
    if (i == 0) {
      #pragma unroll
      for (int d = 60; d < 64; ++d)
        row[(((d>>3) ^ (p&7))<<3) + (d&7)] = 0;
    }
  }
  // ---- biases -> LDS (epilogue never touches vmcnt) ----
  for (int i = tid; i < 9*256; i += 512) {
    int j = i >> 8, t = i & 255;
    bbuf[i] = (j == 0) ? b0[t] : bh[(j-1)*256 + t];
  }
  __syncthreads();   // clean counters before prefetch choreography

  // B-frag base byte offsets (addr(KK,ni) = boff[ni] ^ (KK<<5))
  unsigned boff[NTL];
  #pragma unroll
  for (int ni = 0; ni < NTL; ++ni) {
    int pp = ni*16 + lo;
    boff[ni] = (unsigned)(pp*256 + ((hi ^ (pp&7))<<3));
  }
  const unsigned voff = (unsigned)(w*1024 + lane*16);   // invariant A-load voffset
  i64x2 S0,S1,S2,S3,S4,S5,S6,S7;
  f32x4 acc[2][NTL];

#define GLD1(ra,cc) do{ \
  const unsigned char* s_ = Wt + ((size_t)(cc))*8192; \
  asm volatile("global_load_dwordx4 %0, %1, %2" \
    : "=&v"(ra) : "v"(voff), "s"(s_)); }while(0)

// paired gate: B reads for BOTH chunks -> one vmcnt(WN) -> 8*NTL/2 MFMAs -> optional reissue pair
#define STEP2R(ra,rb,KA,KB,NCA) do{ \
  long bfrA_[NTL], bfrB_[NTL]; \
  _Pragma("unroll") \
  for(int ni=0;ni<NTL;++ni){ \
    bfrA_[ni] = *(const long*)((const char*)hbuf + (boff[ni] ^ ((unsigned)(KA)<<5))); \
    bfrB_[ni] = *(const long*)((const char*)hbuf + (boff[ni] ^ ((unsigned)(KB)<<5))); } \
  asm volatile("s_waitcnt vmcnt(6)":::"memory"); \
  __builtin_amdgcn_sched_barrier(0); \
  _Pragma("unroll") \
  for(int ni=0;ni<NTL;++ni){ \
    acc[0][ni]=__builtin_amdgcn_mfma_f32_16x16x32_fp8_fp8(ra[0],bfrA_[ni],acc[0][ni],0,0,0); \
    acc[1][ni]=__builtin_amdgcn_mfma_f32_16x16x32_fp8_fp8(ra[1],bfrA_[ni],acc[1][ni],0,0,0); \
    acc[0][ni]=__builtin_amdgcn_mfma_f32_16x16x32_fp8_fp8(rb[0],bfrB_[ni],acc[0][ni],0,0,0); \
    acc[1][ni]=__builtin_amdgcn_mfma_f32_16x16x32_fp8_fp8(rb[1],bfrB_[ni],acc[1][ni],0,0,0); } \
  __builtin_amdgcn_sched_barrier(0); \
  GLD1(ra,(NCA)); GLD1(rb,(NCA)+1); \
}while(0)

#define STEP2F(ra,rb,KA,KB,WN) do{ \
  long bfrA_[NTL], bfrB_[NTL]; \
  _Pragma("unroll") \
  for(int ni=0;ni<NTL;++ni){ \
    bfrA_[ni] = *(const long*)((const char*)hbuf + (boff[ni] ^ ((unsigned)(KA)<<5))); \
    bfrB_[ni] = *(const long*)((const char*)hbuf + (boff[ni] ^ ((unsigned)(KB)<<5))); } \
  asm volatile("s_waitcnt vmcnt(" #WN ")":::"memory"); \
  __builtin_amdgcn_sched_barrier(0); \
  _Pragma("unroll") \
  for(int ni=0;ni<NTL;++ni){ \
    acc[0][ni]=__builtin_amdgcn_mfma_f32_16x16x32_fp8_fp8(ra[0],bfrA_[ni],acc[0][ni],0,0,0); \
    acc[1][ni]=__builtin_amdgcn_mfma_f32_16x16x32_fp8_fp8(ra[1],bfrA_[ni],acc[1][ni],0,0,0); \
    acc[0][ni]=__builtin_amdgcn_mfma_f32_16x16x32_fp8_fp8(rb[0],bfrB_[ni],acc[0][ni],0,0,0); \
    acc[1][ni]=__builtin_amdgcn_mfma_f32_16x16x32_fp8_fp8(rb[1],bfrB_[ni],acc[1][ni],0,0,0); } \
  __builtin_amdgcn_sched_barrier(0); \
}while(0)

  auto zacc = [&]() {
    const f32x4 z4 = {0.f,0.f,0.f,0.f};
    #pragma unroll
    for (int mi=0;mi<2;++mi)
      #pragma unroll
      for (int ni=0;ni<NTL;++ni) acc[mi][ni] = z4;
  };
  auto epilogue = [&](int l, bool relu) {
    const float* bias = &bbuf[l*256];
    #pragma unroll
    for (int mi=0;mi<2;++mi) {
      int mt = w*2+mi;
      f32x4 bv = *(const f32x4*)&bias[mt*16 + hi*4];   // LDS read (lgkm)
      #pragma unroll
      for (int ni=0;ni<NTL;++ni) {
        f32x4 v = acc[mi][ni];
        float o0=v[0]+bv[0], o1=v[1]+bv[1], o2=v[2]+bv[2], o3=v[3]+bv[3];
        if (relu){o0=fmaxf(o0,0.f);o1=fmaxf(o1,0.f);o2=fmaxf(o2,0.f);o3=fmaxf(o3,0.f);}
        unsigned pk = (unsigned)__builtin_amdgcn_cvt_pk_fp8_f32(o0, o1, 0, false);
        pk = (unsigned)__builtin_amdgcn_cvt_pk_fp8_f32(o2, o3, (int)pk, true);
        int pp = ni*16 + lo;
        int colu = mt*16 + hi*4;
        int sl = colu >> 3, off = colu & 7;
        *(unsigned*)((char*)hbuf + pp*256 + ((sl^(pp&7))<<3) + off) = pk;
      }
    }
  };

  // prologue: 8 chunks (8 loads) in flight
  GLD1(S0,0); GLD1(S1,1); GLD1(S2,2); GLD1(S3,3);
  GLD1(S4,4); GLD1(S5,5); GLD1(S6,6); GLD1(S7,7);

  // ---- layer 0: chunks 0,1 in one gate; reissue 8,9 ----
  zacc();
  STEP2R(S0,S1, 0,1, 8);
  __builtin_amdgcn_s_barrier();
  epilogue(0, true);
  asm volatile("s_waitcnt lgkmcnt(0)":::"memory");
  __builtin_amdgcn_sched_barrier(0);
  __builtin_amdgcn_s_barrier();

  // ---- layers 1..7: 4 paired gates each; ring slots (2,3)(4,5)(6,7)(0,1); reissue next layer ----
  #pragma unroll 1
  for (int l = 1; l < 8; ++l) {
    zacc();
    const int nx = 2 + l*8;   // next layer's chunk base
    STEP2R(S2,S3, 0,1, nx+0);
    STEP2R(S4,S5, 2,3, nx+2);
    STEP2R(S6,S7, 4,5, nx+4);
    STEP2R(S0,S1, 6,7, nx+6);
    __builtin_amdgcn_s_barrier();   // all waves done reading hbuf
    epilogue(l, true);
    asm volatile("s_waitcnt lgkmcnt(0)":::"memory");
    __builtin_amdgcn_sched_barrier(0);
    __builtin_amdgcn_s_barrier();   // new h visible
  }

  // ---- layer 8: drain tail (no reissue; counted drain 6/4/2/0) ----
  zacc();
  STEP2F(S2,S3, 0,1, 6);
  STEP2F(S4,S5, 2,3, 4);
  STEP2F(S6,S7, 4,5, 2);
  STEP2F(S0,S1, 6,7, 0);
  __builtin_amdgcn_s_barrier();
  epilogue(8, false);
  asm volatile("s_waitcnt lgkmcnt(0)":::"memory");
  __builtin_amdgcn_sched_barrier(0);
  __builtin_amdgcn_s_barrier();
#undef GLD1
#undef STEP2R
#undef STEP2F

  // ---- heads: 4 threads per point, 64 k each; fp32 head weights, fp8 h ----
  if (tid < NTL*64) {
    int p = tid >> 2, s = tid & 3;
    float as_=0.f, a0=0.f, a1=0.f, a2=0.f;
    for (int q=0;q<8;++q) {
      int slot = s*8+q;
      const unsigned char* hb = &hbuf[p*256 + ((slot^(p&7))<<3)];
      #pragma unroll
      for (int j=0;j<8;++j) {
        float hf = e4m3f(hb[j]);
        int k = s*64 + q*8 + j;
        as_ = fmaf(hf, Wsig[k], as_);
        const float* wc = Wcol + 72 + k*3;
        a0 = fmaf(hf, wc[0], a0);
        a1 = fmaf(hf, wc[1], a1);
        a2 = fmaf(hf, wc[2], a2);
      }
    }
    as_ += __shfl_xor(as_,1); as_ += __shfl_xor(as_,2);
    a0 += __shfl_xor(a0,1); a0 += __shfl_xor(a0,2);
    a1 += __shfl_xor(a1,1); a1 += __shfl_xor(a1,2);
    a2 += __shfl_xor(a2,1); a2 += __shfl_xor(a2,2);
    if (s == 0) {
      sig_out[p0+p] = 1.f/(1.f+expf(-(as_ + bsig[0])));
      col_out[0*npts + p0+p] = 1.f/(1.f+expf(-(a0 + cst[6])));
      col_out[1*npts + p0+p] = 1.f/(1.f+expf(-(a1 + cst[7])));
      col_out[2*npts + p0+p] = 1.f/(1.f+expf(-(a2 + cst[8])));
    }
  }
}

// ---------------- mid: redundant block-local scan + ccoarse partials (blocks<8) + invcdf (16 blocks) ----------------
__global__ __launch_bounds__(1024) void k_mid(
    const float* __restrict__ sigco, const float* __restrict__ colco,
    const float* __restrict__ cst, float* __restrict__ tfine,
    float* __restrict__ cpart2)
{
  __shared__ float cdf[NC];   // 32 KB
  __shared__ float wsum[16];
  __shared__ float r0[16], r1[16], r2[16];
  const int tid = threadIdx.x;
  const int lane = tid & 63, wid = tid >> 6;

  // block-local scan of sigco (identical arithmetic in every block -> deterministic)
  float v[8], inc[8];
  float run = 0.f;
  #pragma unroll
  for (int j = 0; j < 8; ++j) { v[j] = sigco[tid*8+j]; run += v[j]; inc[j] = run; }
  float sc = run;
  #pragma unroll
  for (int off = 1; off < 64; off <<= 1) {
    float t = __shfl_up(sc, off);
    if (lane >= off) sc += t;
  }
  if (lane == 63) wsum[wid] = sc;
  __syncthreads();
  if (tid < 16) {
    float wv = wsum[tid];
    float s2 = wv;
    #pragma unroll
    for (int off = 1; off < 16; off <<= 1) {
      float t = __shfl_up(s2, off);
      if (tid >= off) s2 += t;
    }
    wsum[tid] = s2 - wv;
  }
  __syncthreads();
  float excl = wsum[wid] + (sc - run);
  #pragma unroll
  for (int j = 0; j < 8; ++j) cdf[tid*8+j] = excl + inc[j];
  __syncthreads();

  // blocks 0..7: C_coarse partials for their 1024-element slice
  if (blockIdx.x < 8) {
    int i = blockIdx.x*1024 + tid;
    float dco = cst[11];
    float T = expf(-dco*cdf[i]);
    float w = T*(1.f-expf(-dco*sigco[i]));
    float a0 = colco[i]*w, a1 = colco[NC+i]*w, a2 = colco[2*NC+i]*w;
    #pragma unroll
    for (int off = 32; off; off >>= 1) {
      a0 += __shfl_down(a0, off); a1 += __shfl_down(a1, off); a2 += __shfl_down(a2, off);
    }
    if (lane==0) { r0[wid]=a0; r1[wid]=a1; r2[wid]=a2; }
    __syncthreads();
    if (tid==0) {
      float s0=0,s1=0,s2=0;
      for (int k=0;k<16;++k){s0+=r0[k];s1+=r1[k];s2+=r2[k];}
      cpart2[blockIdx.x*3+0]=s0; cpart2[blockIdx.x*3+1]=s1; cpart2[blockIdx.x*3+2]=s2;
    }
  }

  // all 16 blocks: inverse-CDF for their 1024 samples (LDS-resident cdf)
  int j = blockIdx.x*1024 + tid;
  float cdf0 = cdf[0], cdfN = cdf[NC-1];
  float stepi = (cdfN - cdf0) / (float)(NF+1);
  float nearv = cst[9], dt = cst[10];
  float tv = cdf0 + (float)(j+1)*stepi;
  int lo = 0, hi = NC;
  while (lo < hi) { int mid = (lo+hi)>>1; if (cdf[mid] < tv) lo = mid+1; else hi = mid; }
  int idx = lo-1; idx = idx < 0 ? 0 : (idx > NC-2 ? NC-2 : idx);
  float sig1 = sigco[idx+1];
  tfine[j] = fmaf(dt, (float)idx, nearv) + (tv - cdf[idx]) * (dt / sig1);
}

// ---------------- radix sort: 16 blocks (4 arrays x 4 quarters of 6144), keys in regs ----------------
__global__ __launch_bounds__(1024) void k_radix4(
    const float* __restrict__ sigco, const float* __restrict__ colco,
    const float* __restrict__ sigfi, const float* __restrict__ colfi,
    float* __restrict__ rad4)
{
  __shared__ unsigned int buf[QN];       // 24KB
  __shared__ unsigned int wh[16][256];   // 16KB
  __shared__ unsigned int tot[256];
  __shared__ unsigned int dbase[256];
  const int tid = threadIdx.x;
  const int w = tid >> 6, lane = tid & 63;
  const int a = blockIdx.x >> 2, qq = blockIdx.x & 3;
  const unsigned long long below = (1ull << lane) - 1ull;

  unsigned int key[6];
  #pragma unroll
  for (int j = 0; j < 6; ++j) {
    int i = w*384 + j*64 + lane;   // enumeration order = storage order
    int g = qq*QN + i;
    float v;
    if (a < 3) v = (g < NC) ? colco[a*NC+g] : colfi[a*NF + (g-NC)];
    else       v = (g < NC) ? sigco[g] : sigfi[g-NC];
    key[j] = __float_as_uint(v);
  }

  for (int p = 0; p < 4; ++p) {
    const int sh = p*8;
    for (int i = tid; i < 16*256; i += 1024) ((unsigned int*)wh)[i] = 0;
    __syncthreads();
    unsigned int lrk[6];
    #pragma unroll
    for (int j = 0; j < 6; ++j) {
      unsigned int d = (key[j] >> sh) & 255u;
      unsigned long long m = ~0ull;
      #pragma unroll
      for (int b = 0; b < 8; ++b) {
        unsigned long long bb = __ballot((d >> b) & 1u);
        m &= ((d >> b) & 1u) ? bb : ~bb;
      }
      unsigned int rkl = (unsigned int)__popcll(m & below);
      unsigned int base = wh[w][d];
      if (rkl == 0) wh[w][d] = base + (unsigned int)__popcll(m);
      lrk[j] = base + rkl;
    }
    __syncthreads();
    if (tid < 256) {
      unsigned int run2 = 0;
      #pragma unroll
      for (int ww = 0; ww < 16; ++ww) { unsigned int c = wh[ww][tid]; wh[ww][tid] = run2; run2 += c; }
      tot[tid] = run2;
    }
    __syncthreads();
    if (tid < 64) {
      unsigned int t0=tot[tid*4], t1=tot[tid*4+1], t2=tot[tid*4+2], t3=tot[tid*4+3];
      unsigned int ssum = t0+t1+t2+t3;
      unsigned int sc = ssum;
      for (int off=1; off<64; off<<=1) { unsigned int vv = __shfl_up((int)sc, off); if (lane>=off) sc += vv; }
      unsigned int ex = sc - ssum;
      dbase[tid*4] = ex; dbase[tid*4+1] = ex+t0; dbase[tid*4+2] = ex+t0+t1; dbase[tid*4+3] = ex+t0+t1+t2;
    }
    __syncthreads();
    #pragma unroll
    for (int j = 0; j < 6; ++j) {
      unsigned int d = (key[j] >> sh) & 255u;
      buf[dbase[d] + wh[w][d] + lrk[j]] = key[j];
    }
    __syncthreads();
    if (p < 3) {
      #pragma unroll
      for (int j = 0; j < 6; ++j) key[j] = buf[w*384 + j*64 + lane];
      __syncthreads();
    }
  }
  for (int i = tid; i < QN; i += 1024)
    rad4[a*NT + qq*QN + i] = __uint_as_float(buf[i]);
}

// ---------------- merge quarters -> halves: 16 blocks (4 arrays x 2 halves x 2 segs) ----------------
__global__ __launch_bounds__(1024) void k_merge2(
    const float* __restrict__ rad4, float* __restrict__ rad)
{
  const int a = blockIdx.x >> 2, h = (blockIdx.x >> 1) & 1, s = blockIdx.x & 1;
  const float* A = rad4 + a*NT + (2*h)*QN;
  const float* B = A + QN;
  float* o = rad + a*NT + h*RN;
  int k0 = s*QN + (int)threadIdx.x*6;
  int lo = k0-QN; if (lo < 0) lo = 0;
  int hi = k0 < QN ? k0 : QN;
  while (lo < hi) {
    int mid = (lo+hi)>>1;
    if (A[mid] <= B[k0-mid-1]) lo = mid+1; else hi = mid;
  }
  int i = lo, j = k0 - lo;
  #pragma unroll
  for (int c = 0; c < 6; ++c) {
    float av = (i < QN) ? A[i] : 0.f;
    bool ta = (j >= QN) || (i < QN && av <= B[j]);
    float v = ta ? av : B[j];
    if (ta) ++i; else ++j;
    o[k0+c] = v;
  }
}

// ---------------- merge: 5 rows; row0 = t_coarse(analytic) ∪ t_fine; rows1-4 = sorted halves ----------------
__global__ __launch_bounds__(1024) void k_merge(
    const float* __restrict__ rad, const float* __restrict__ tfine,
    const float* __restrict__ cst, float* __restrict__ srt)
{
  const int row = blockIdx.x >> 2, q = blockIdx.x & 3;
  const float dt = cst[10], nv = cst[9];
  const bool isT = (row == 0);
  const float* A = isT ? (const float*)nullptr : rad + (row-1)*NT;
  const float* B = isT ? tfine : (A + RN);
  const int nA = isT ? NC : RN, nB = isT ? NF : RN;
  int k0 = q*6144 + (int)threadIdx.x*6;
  int lo = k0-nB; if (lo < 0) lo = 0;
  int hi = k0 < nA ? k0 : nA;
  while (lo < hi) {
    int mid = (lo+hi)>>1;
    float av = isT ? fmaf(dt,(float)mid,nv) : A[mid];
    if (av <= B[k0-mid-1]) lo = mid+1; else hi = mid;
  }
  int i = lo, j = k0 - lo;
  float* o = srt + row*NT;
  #pragma unroll
  for (int c = 0; c < 6; ++c) {
    float av = (i < nA) ? (isT ? fmaf(dt,(float)i,nv) : A[i]) : 0.f;
    bool ta = (j >= nB) || (i < nA && av <= B[j]);
    float v = ta ? av : B[j];
    if (ta) ++i; else ++j;
    o[k0+c] = v;
  }
}

// ---------------- final phase 1: per-block sd sums (24 blocks x 1024) ----------------
__global__ __launch_bounds__(1024) void k_fpart(
    const float* __restrict__ srt, float* __restrict__ fpart)
{
  const float* trow = srt;
  const float* sgr = srt + 4*NT;
  __shared__ float wsum[16];
  int i = blockIdx.x*1024 + threadIdx.x;
  const int lane = threadIdx.x & 63, wid = threadIdx.x >> 6;
  float tcur = trow[i];
  float tnext = (i < NT-1) ? trow[i+1] : 0.f;
  float delta = (i == NT-1) ? LASTD : (tnext - tcur);
  float sd = delta * sgr[i];
  float s = sd;
  #pragma unroll
  for (int off = 32; off; off >>= 1) s += __shfl_down(s, off);
  if (lane == 0) wsum[wid] = s;
  __syncthreads();
  if (threadIdx.x == 0) {
    float t = 0.f;
    for (int k = 0; k < 16; ++k) t += wsum[k];
    fpart[blockIdx.x] = t;
  }
}

// ---------------- final phase 2: offset + local scan + weighted color partials ----------------
__global__ __launch_bounds__(1024) void k_fcomb(
    const float* __restrict__ srt, const float* __restrict__ fpart,
    float* __restrict__ cpart)
{
  const float* trow = srt;
  const float* c0r = srt + NT;
  const float* c1r = srt + 2*NT;
  const float* c2r = srt + 3*NT;
  const float* sgr = srt + 4*NT;
  __shared__ float wsum[16];
  __shared__ float r0[16], r1[16], r2[16];
  const int tid = threadIdx.x;
  const int lane = tid & 63, wid = tid >> 6;
  int i = blockIdx.x*1024 + tid;
  float off0 = 0.f;
  for (int k = 0; k < 24; ++k) off0 += (k < (int)blockIdx.x) ? fpart[k] : 0.f;

  float tcur = trow[i];
  float tnext = (i < NT-1) ? trow[i+1] : 0.f;
  float delta = (i == NT-1) ? LASTD : (tnext - tcur);
  float sd = delta * sgr[i];
  // block inclusive scan of sd
  float sc = sd;
  #pragma unroll
  for (int off = 1; off < 64; off <<= 1) {
    float t = __shfl_up(sc, off);
    if (lane >= off) sc += t;
  }
  if (lane == 63) wsum[wid] = sc;
  __syncthreads();
  if (tid < 16) {
    float wv = wsum[tid];
    float s2 = wv;
    #pragma unroll
    for (int off = 1; off < 16; off <<= 1) {
      float t = __shfl_up(s2, off);
      if (tid >= off) s2 += t;
    }
    wsum[tid] = s2 - wv;
  }
  __syncthreads();
  float Sinc = off0 + wsum[wid] + sc;   // global inclusive cumsum at i
  float T = expf(-Sinc);
  float w = T*(1.f-expf(-sd));
  float a0 = c0r[i]*w, a1 = c1r[i]*w, a2 = c2r[i]*w;
  #pragma unroll
  for (int off = 32; off; off >>= 1) {
    a0 += __shfl_down(a0, off); a1 += __shfl_down(a1, off); a2 += __shfl_down(a2, off);
  }
  if (lane==0) { r0[wid]=a0; r1[wid]=a1; r2[wid]=a2; }
  __syncthreads();
  if (tid==0) {
    float s0=0,s1=0,s2=0;
    for (int k=0;k<16;++k){s0+=r0[k];s1+=r1[k];s2+=r2[k];}
    cpart[blockIdx.x*3+0]=s0; cpart[blockIdx.x*3+1]=s1; cpart[blockIdx.x*3+2]=s2;
  }
}

// ---------------- final phase 3: sum partials (coarse 8, fine 24) ----------------
__global__ void k_fsum(const float* __restrict__ cpart, const float* __restrict__ cpart2,
                       float* __restrict__ outv)
{
  int c = threadIdx.x;
  if (c < 3) {
    float s2 = 0.f;
    for (int b = 0; b < 8; ++b) s2 += cpart2[b*3 + c];
    outv[c] = s2;
    float s = 0.f;
    for (int b = 0; b < 24; ++b) s += cpart[b*3 + c];
    outv[3 + c] = s;
  }
}

extern "C" void kernel_launch(void* const* d_in, const int* in_sizes, int n_in,
                              void* d_out, int out_size, void* d_ws, size_t ws_size,
                              hipStream_t stream) {
  (void)in_sizes; (void)n_in; (void)out_size; (void)ws_size;
  const float* hor  = (const float*)d_in[0];
  const float* ver  = (const float*)d_in[1];
  const float* tm   = (const float*)d_in[2];
  const float* nearp= (const float*)d_in[3];
  const float* farp = (const float*)d_in[4];
  const float* W0   = (const float*)d_in[5];
  const float* b0   = (const float*)d_in[6];
  const float* Wh   = (const float*)d_in[7];
  const float* bh   = (const float*)d_in[8];
  const float* Wsig = (const float*)d_in[9];
  const float* bsig = (const float*)d_in[10];
  const float* Wcol = (const float*)d_in[11];
  const float* bcol = (const float*)d_in[12];
  float* out = (float*)d_out;
  float* ws  = (float*)d_ws;

  float* cst   = ws + WS_CONST;
  float* tfine = ws + WS_TFINE;
  float* sigco = ws + WS_SIGCO;
  float* colco = ws + WS_COLCO;
  float* sigfi = ws + WS_SIGFI;
  float* colfi = ws + WS_COLFI;
  float* srt   = ws + WS_SRT;
  float* rad   = ws + WS_RAD;
  float* fpart = ws + WS_FP;
  float* cpart = ws + WS_CP;
  float* cpart2= ws + WS_CP2;
  float* rad4  = ws + WS_RAD4;
  unsigned char* Wt = (unsigned char*)(ws + WS_WT);

  k_prep_w<<<dim3(529), dim3(256), 0, stream>>>(W0, Wh, Wt, hor, ver, tm, nearp, farp,
                                                Wcol, bcol, cst);
  k_mlp_mfma<2><<<dim3(NC/32), dim3(512), 0, stream>>>(cst, Wt, b0, bh, Wsig, bsig, Wcol,
                                                       (const float*)nullptr, NC, sigco, colco);
  k_mid<<<dim3(16), dim3(1024), 0, stream>>>(sigco, colco, cst, tfine, cpart2);
  k_mlp_mfma<2><<<dim3(NF/32), dim3(512), 0, stream>>>(cst, Wt, b0, bh, Wsig, bsig, Wcol,
                                                       (const float*)tfine, NF, sigfi, colfi);
  k_radix4<<<dim3(16), dim3(1024), 0, stream>>>(sigco, colco, sigfi, colfi, rad4);
  k_merge2<<<dim3(16), dim3(1024), 0, stream>>>(rad4, rad);
  k_merge<<<dim3(20), dim3(1024), 0, stream>>>(rad, tfine, cst, srt);
  k_fpart<<<dim3(24), dim3(1024), 0, stream>>>(srt, fpart);
  k_fcomb<<<dim3(24), dim3(1024), 0, stream>>>(srt, fpart, cpart);
  k_fsum<<<dim3(1), dim3(64), 0, stream>>>(cpart, cpart2, out);
}